// Round 5
// baseline (984.748 us; speedup 1.0000x reference)
//
#include <hip/hip_runtime.h>

// GCN restructure:  deg[c] = 1 + sum_{col=c} w;  dinv = rsqrt(deg)
//   g = (X@W) * dinv[node]        (GEMM epilogue, stored bf16)
//   out[c] = relu( dinv[c] * ( g[c] + sum_{e: col=c} w_e * g[row_e] ) + b )
//
// R5: ZERO global data atomics.  Edges are counting-sorted into 128-node
// coarse buckets (per-block LDS histograms + 2 tiny scan kernels + exact-slot
// scatter).  Aggregation: one block per bucket, 32KB LDS f32 accumulators
// (bank-swizzled), coalesced edge reads, bf16 gathers, fused relu epilogue.
// Measured basis: each global atomic costs ~62B memory-side traffic (R3/R4).

#define BNODES 128
#define LB 7                 // log2(BNODES)
#define MAXBKT 1024          // supports n <= 131072
#define EPT 16
#define EPB (256 * EPT)      // 4096 edges per sort block -> NEB <= 256 for E <= 1M

__device__ __forceinline__ unsigned short f2bf(float f) {
    unsigned u = __float_as_uint(f);
    u = (u + 0x7FFF + ((u >> 16) & 1)) >> 16;
    return (unsigned short)u;
}
__device__ __forceinline__ float bf2f(unsigned short h) {
    return __uint_as_float(((unsigned)h) << 16);
}

__device__ __forceinline__ int waveIncScan(int v, int lane) {
    #pragma unroll
    for (int d = 1; d < 64; d <<= 1) {
        int u = __shfl_up(v, d, 64);
        if (lane >= d) v += u;
    }
    return v;
}

// inclusive scan across 256 threads (4 waves)
__device__ __forceinline__ int blockIncScan(int v, int t, int* wt) {
    int lane = t & 63, w = t >> 6;
    int s = waveIncScan(v, lane);
    if (lane == 63) wt[w] = s;
    __syncthreads();
    int add = 0;
    #pragma unroll
    for (int i = 0; i < 3; ++i) if (i < w) add += wt[i];
    return s + add;
}

// ---- sort pipeline -------------------------------------------------------

// per-block histogram over coarse buckets
__global__ __launch_bounds__(256) void hist_kernel(
    const int* __restrict__ col, int* __restrict__ H, int E, int NBKT)
{
    __shared__ int h[MAXBKT];
    int t = threadIdx.x, blk = blockIdx.x;
    for (int b = t; b < NBKT; b += 256) h[b] = 0;
    __syncthreads();
    int base = blk * EPB;
    #pragma unroll
    for (int i = 0; i < EPT; ++i) {
        int e = base + i * 256 + t;
        if (e < E) atomicAdd(&h[col[e] >> LB], 1);
    }
    __syncthreads();
    for (int b = t; b < NBKT; b += 256) H[blk * NBKT + b] = h[b];
}

// exclusive scan of each bucket's per-block counts (NEB <= 256)
__global__ __launch_bounds__(256) void rowscan_kernel(
    int* __restrict__ H, int* __restrict__ rowSum, int NEB, int NBKT)
{
    __shared__ int wt[4];
    int b = blockIdx.x, t = threadIdx.x;
    int v = (t < NEB) ? H[t * NBKT + b] : 0;
    int incl = blockIncScan(v, t, wt);
    if (t < NEB) H[t * NBKT + b] = incl - v;
    if (t == 255) rowSum[b] = incl;
}

// exclusive scan of bucket totals (NBKT <= 1024), one block
__global__ __launch_bounds__(256) void bktscan_kernel(
    const int* __restrict__ rowSum, int* __restrict__ bktStart, int NBKT)
{
    __shared__ int wt[4];
    int t = threadIdx.x;
    int v[4]; int sum = 0;
    #pragma unroll
    for (int k = 0; k < 4; ++k) {
        int i = t * 4 + k;
        v[k] = (i < NBKT) ? rowSum[i] : 0;
        sum += v[k];
    }
    int incl = blockIncScan(sum, t, wt);
    int excl = incl - sum;
    #pragma unroll
    for (int k = 0; k < 4; ++k) {
        int i = t * 4 + k;
        if (i < NBKT) bktStart[i] = excl;
        excl += v[k];
    }
    if (t == 255) bktStart[NBKT] = incl;   // grand total = E
}

// scatter each edge to its exact reserved slot (LDS cursors, no global atomics)
// pack: x = row | (local_dest << 20), y = weight bits     (needs n < 2^20)
__global__ __launch_bounds__(256) void scatter_kernel(
    const int* __restrict__ row, const int* __restrict__ col,
    const float* __restrict__ w, const int* __restrict__ H,
    const int* __restrict__ bktStart, int2* __restrict__ sedge, int E, int NBKT)
{
    __shared__ int cur[MAXBKT];
    int t = threadIdx.x, blk = blockIdx.x;
    for (int b = t; b < NBKT; b += 256) cur[b] = bktStart[b] + H[blk * NBKT + b];
    __syncthreads();
    int base = blk * EPB;
    #pragma unroll
    for (int i = 0; i < EPT; ++i) {
        int e = base + i * 256 + t;
        if (e < E) {
            int c = col[e];
            int b = c >> LB;
            int pos = atomicAdd(&cur[b], 1);      // LDS atomic
            int2 pk;
            pk.x = row[e] | ((c & (BNODES - 1)) << 20);
            pk.y = __float_as_int(w[e]);
            sedge[pos] = pk;
        }
    }
}

// dinv[node] = rsqrt(1 + sum of incident weights), per bucket via LDS
__global__ __launch_bounds__(256) void dinv_kernel(
    const int2* __restrict__ sedge, const int* __restrict__ bktStart,
    float* __restrict__ dinv, int n)
{
    __shared__ float deg[BNODES];
    int b = blockIdx.x, t = threadIdx.x;
    if (t < BNODES) deg[t] = 1.0f;
    __syncthreads();
    int s = bktStart[b], e = bktStart[b + 1];
    for (int j = s + t; j < e; j += 256) {
        int2 pk = sedge[j];
        atomicAdd(&deg[pk.x >> 20], __int_as_float(pk.y));
    }
    __syncthreads();
    int node = b * BNODES + t;
    if (t < BNODES && node < n) dinv[node] = rsqrtf(deg[t]);
}

// ---- per-layer kernels ---------------------------------------------------

// G[node,:] = bf16( (X[node,:] @ W) * dinv[node] )   (64x64 tile per block)
template<int K>
__global__ __launch_bounds__(256) void gemm_scale_kernel(
    const float* __restrict__ X, const float* __restrict__ W,
    const float* __restrict__ dinv, unsigned short* __restrict__ G, int n)
{
    __shared__ float xs[64][K + 1];
    __shared__ float ws[K][64];
    const int tid = threadIdx.x;
    const int nodeBase = blockIdx.x * 64;

    for (int idx = tid; idx < K * 16; idx += 256) {
        int flat = idx * 4;
        int k = flat >> 6, c = flat & 63;
        *(float4*)&ws[k][c] = *(const float4*)&W[flat];
    }
    for (int idx = tid; idx < 16 * K; idx += 256) {
        int flat = idx * 4;
        int r = flat / K, c = flat % K;
        int node = nodeBase + r;
        float4 v = make_float4(0.f, 0.f, 0.f, 0.f);
        if (node < n) v = *(const float4*)&X[(size_t)node * K + c];
        *(float4*)&xs[r][c] = v;
    }
    __syncthreads();

    const int nr = tid >> 4;
    const int fc = tid & 15;
    float acc[4][4];
    #pragma unroll
    for (int m = 0; m < 4; ++m)
        #pragma unroll
        for (int j = 0; j < 4; ++j) acc[m][j] = 0.f;

    #pragma unroll 4
    for (int k = 0; k < K; ++k) {
        float4 b = *(const float4*)&ws[k][fc * 4];
        #pragma unroll
        for (int m = 0; m < 4; ++m) {
            float a = xs[nr * 4 + m][k];
            acc[m][0] = fmaf(a, b.x, acc[m][0]);
            acc[m][1] = fmaf(a, b.y, acc[m][1]);
            acc[m][2] = fmaf(a, b.z, acc[m][2]);
            acc[m][3] = fmaf(a, b.w, acc[m][3]);
        }
    }

    #pragma unroll
    for (int m = 0; m < 4; ++m) {
        int node = nodeBase + nr * 4 + m;
        if (node >= n) continue;
        float s = dinv[node];
        ushort4 v;
        v.x = f2bf(acc[m][0] * s);
        v.y = f2bf(acc[m][1] * s);
        v.z = f2bf(acc[m][2] * s);
        v.w = f2bf(acc[m][3] * s);
        *(ushort4*)&G[(size_t)node * 64 + fc * 4] = v;
    }
}

// one block per 128-node bucket; 32KB LDS f32 accumulators (bank-swizzled);
// 16 lanes per edge, 4-deep gather MLP; fused relu epilogue.
__global__ __launch_bounds__(256) void agg_kernel(
    const unsigned short* __restrict__ G, const int2* __restrict__ sedge,
    const int* __restrict__ bktStart, const float* __restrict__ dinv,
    const float* __restrict__ bias, float* __restrict__ OUT, int n)
{
    __shared__ float acc[BNODES * 64];   // 32 KB
    int b = blockIdx.x, t = threadIdx.x;
    float4* accv = (float4*)acc;
    for (int i = t; i < BNODES * 16; i += 256) accv[i] = make_float4(0.f, 0.f, 0.f, 0.f);
    __syncthreads();

    int s = bktStart[b], eEnd = bktStart[b + 1];
    int sub = t >> 4, p = t & 15;

    for (int base = s; base < eEnd; base += 64) {
        int2 m[4];
        ushort4 g[4];
        #pragma unroll
        for (int k = 0; k < 4; ++k) {
            int e = base + k * 16 + sub;
            int2 pk = make_int2(0, 0);
            if (e < eEnd) pk = sedge[e];
            m[k] = pk;
        }
        #pragma unroll
        for (int k = 0; k < 4; ++k) {
            int r = m[k].x & 0xFFFFF;
            g[k] = *(const ushort4*)&G[(size_t)r * 64 + p * 4];
        }
        #pragma unroll
        for (int k = 0; k < 4; ++k) {
            float w = __int_as_float(m[k].y);     // 0 for tail slots -> no-op adds
            int ld = m[k].x >> 20;
            int fbase = (p ^ ((ld & 3) << 1)) * 4;   // XOR bank swizzle, float4-preserving
            float* dst = &acc[ld * 64 + fbase];
            atomicAdd(dst + 0, w * bf2f(g[k].x));
            atomicAdd(dst + 1, w * bf2f(g[k].y));
            atomicAdd(dst + 2, w * bf2f(g[k].z));
            atomicAdd(dst + 3, w * bf2f(g[k].w));
        }
    }
    __syncthreads();

    for (int i = t; i < BNODES * 16; i += 256) {
        int loc = i >> 4, pp = i & 15;
        int node = b * BNODES + loc;
        if (node >= n) continue;
        float4 a = *(float4*)&acc[loc * 64 + (pp ^ ((loc & 3) << 1)) * 4];
        ushort4 sv = *(const ushort4*)&G[(size_t)node * 64 + pp * 4];
        float di = dinv[node];
        float4 bb = *(const float4*)&bias[pp * 4];
        float4 o;
        o.x = fmaxf(fmaf(di, a.x + bf2f(sv.x), bb.x), 0.f);
        o.y = fmaxf(fmaf(di, a.y + bf2f(sv.y), bb.y), 0.f);
        o.z = fmaxf(fmaf(di, a.z + bf2f(sv.z), bb.z), 0.f);
        o.w = fmaxf(fmaf(di, a.w + bf2f(sv.w), bb.w), 0.f);
        *(float4*)&OUT[(size_t)node * 64 + pp * 4] = o;
    }
}

extern "C" void kernel_launch(void* const* d_in, const int* in_sizes, int n_in,
                              void* d_out, int out_size, void* d_ws, size_t ws_size,
                              hipStream_t stream) {
    const float* x     = (const float*)d_in[0];
    const int*   eidx  = (const int*)d_in[1];
    const float* eattr = (const float*)d_in[2];
    const float* W1    = (const float*)d_in[3];
    const float* b1    = (const float*)d_in[4];
    const float* W2    = (const float*)d_in[5];
    const float* b2    = (const float*)d_in[6];
    float* out = (float*)d_out;

    const int n = in_sizes[0] / 128;
    const int E = in_sizes[2];
    const int* row = eidx;
    const int* col = eidx + E;

    const int NBKT = (n + BNODES - 1) / BNODES;    // 782 for n=100000
    const int NEB  = (E + EPB - 1) / EPB;          // 245 for E=1e6 (must be <=256)

    // workspace (~22 MB): sedge[E] int2 | gbuf[n*64] bf16 | dinv[n] f32 |
    //                     H[NEB*NBKT] | rowSum[NBKT] | bktStart[NBKT+1]
    int2*  sedge = (int2*)d_ws;
    unsigned short* gbuf = (unsigned short*)(sedge + (size_t)E);
    float* dinv  = (float*)(gbuf + (size_t)n * 64);
    int*   H     = (int*)(dinv + n);
    int*   rowSum = H + (size_t)NEB * NBKT;
    int*   bktStart = rowSum + NBKT;

    const int nbG = (n + 63) / 64;

    // ---- build (once; shared by both layers) -- zero global data atomics
    hist_kernel<<<NEB, 256, 0, stream>>>(col, H, E, NBKT);
    rowscan_kernel<<<NBKT, 256, 0, stream>>>(H, rowSum, NEB, NBKT);
    bktscan_kernel<<<1, 256, 0, stream>>>(rowSum, bktStart, NBKT);
    scatter_kernel<<<NEB, 256, 0, stream>>>(row, col, eattr, H, bktStart, sedge, E, NBKT);
    dinv_kernel<<<NBKT, 256, 0, stream>>>(sedge, bktStart, dinv, n);

    // ---- layer 1: g1 -> gbuf, out1 -> d_out (activation buffer)
    gemm_scale_kernel<128><<<nbG, 256, 0, stream>>>(x, W1, dinv, gbuf, n);
    agg_kernel<<<NBKT, 256, 0, stream>>>(gbuf, sedge, bktStart, dinv, b1, out, n);

    // ---- layer 2: g2 -> gbuf, final -> d_out
    gemm_scale_kernel<64><<<nbG, 256, 0, stream>>>(out, W2, dinv, gbuf, n);
    agg_kernel<<<NBKT, 256, 0, stream>>>(gbuf, sedge, bktStart, dinv, b2, out, n);
}

// Round 6
// 168.832 us; speedup vs baseline: 5.8327x; 5.8327x over previous
//
#include <hip/hip_runtime.h>

// GCN restructure:  deg[c] = 1 + sum_{col=c} w;  dinv = rsqrt(deg)
//   g = (X@W) * dinv[node]        (GEMM epilogue, stored bf16)
//   out[c] = relu( dinv[c] * ( g[c] + sum_{e: col=c} w_e * g[row_e] ) + b )
//
// R6: two-level counting sort -> true CSR (per-node contiguous edge lists),
// ZERO global data atomics, ~2M LDS atomics total (R5's mistake: 128M LDS
// atomic-RMWs in the aggregation = 445us/layer; atomic COUNT matters at every
// level).  Aggregation = R4's register-accumulate (one thread owns 4 output
// features of one node; no atomics anywhere).

#define BNODES 128
#define LB 7                 // log2(BNODES)
#define MAXBKT 1024          // supports n <= 131072
#define EPT 16
#define EPB (256 * EPT)      // 4096 edges per sort block; NEB<=256 for E<=1M

__device__ __forceinline__ unsigned short f2bf(float f) {
    unsigned u = __float_as_uint(f);
    u = (u + 0x7FFF + ((u >> 16) & 1)) >> 16;
    return (unsigned short)u;
}
__device__ __forceinline__ float bf2f(unsigned short h) {
    return __uint_as_float(((unsigned)h) << 16);
}

__device__ __forceinline__ int waveIncScan(int v, int lane) {
    #pragma unroll
    for (int d = 1; d < 64; d <<= 1) {
        int u = __shfl_up(v, d, 64);
        if (lane >= d) v += u;
    }
    return v;
}

// inclusive scan across 256 threads (4 waves); includes __syncthreads
__device__ __forceinline__ int blockIncScan(int v, int t, int* wt) {
    int lane = t & 63, w = t >> 6;
    int s = waveIncScan(v, lane);
    if (lane == 63) wt[w] = s;
    __syncthreads();
    int add = 0;
    #pragma unroll
    for (int i = 0; i < 3; ++i) if (i < w) add += wt[i];
    return s + add;
}

// ---- sort pipeline (zero global atomics) ---------------------------------

__global__ __launch_bounds__(256) void hist_kernel(
    const int* __restrict__ col, int* __restrict__ H, int E, int NBKT)
{
    __shared__ int h[MAXBKT];
    int t = threadIdx.x, blk = blockIdx.x;
    for (int b = t; b < NBKT; b += 256) h[b] = 0;
    __syncthreads();
    int base = blk * EPB;
    #pragma unroll
    for (int i = 0; i < EPT; ++i) {
        int e = base + i * 256 + t;
        if (e < E) atomicAdd(&h[col[e] >> LB], 1);
    }
    __syncthreads();
    for (int b = t; b < NBKT; b += 256) H[blk * NBKT + b] = h[b];
}

// per-bucket exclusive scan over block counts (NEB <= 256)
__global__ __launch_bounds__(256) void rowscan_kernel(
    int* __restrict__ H, int* __restrict__ rowSum, int NEB, int NBKT)
{
    __shared__ int wt[4];
    int b = blockIdx.x, t = threadIdx.x;
    int v = (t < NEB) ? H[t * NBKT + b] : 0;
    int incl = blockIncScan(v, t, wt);
    if (t < NEB) H[t * NBKT + b] = incl - v;
    if (t == 255) rowSum[b] = incl;
}

// exclusive scan of bucket totals (NBKT <= 1024), one block
__global__ __launch_bounds__(256) void bktscan_kernel(
    const int* __restrict__ rowSum, int* __restrict__ bktStart, int NBKT)
{
    __shared__ int wt[4];
    int t = threadIdx.x;
    int v[4]; int sum = 0;
    #pragma unroll
    for (int k = 0; k < 4; ++k) {
        int i = t * 4 + k;
        v[k] = (i < NBKT) ? rowSum[i] : 0;
        sum += v[k];
    }
    int incl = blockIncScan(sum, t, wt);
    int excl = incl - sum;
    #pragma unroll
    for (int k = 0; k < 4; ++k) {
        int i = t * 4 + k;
        if (i < NBKT) bktStart[i] = excl;
        excl += v[k];
    }
    if (t == 255) bktStart[NBKT] = incl;
}

// coarse scatter: each edge to its exact reserved slot in its 128-node bucket
// pack: x = row | (local_dest << 20), y = weight bits   (needs n < 2^20)
__global__ __launch_bounds__(256) void scatter_kernel(
    const int* __restrict__ row, const int* __restrict__ col,
    const float* __restrict__ w, const int* __restrict__ H,
    const int* __restrict__ bktStart, int2* __restrict__ sedge1, int E, int NBKT)
{
    __shared__ int cur[MAXBKT];
    int t = threadIdx.x, blk = blockIdx.x;
    for (int b = t; b < NBKT; b += 256) cur[b] = bktStart[b] + H[blk * NBKT + b];
    __syncthreads();
    int base = blk * EPB;
    #pragma unroll
    for (int i = 0; i < EPT; ++i) {
        int e = base + i * 256 + t;
        if (e < E) {
            int c = col[e];
            int b = c >> LB;
            int pos = atomicAdd(&cur[b], 1);      // LDS atomic
            int2 pk;
            pk.x = row[e] | ((c & (BNODES - 1)) << 20);
            pk.y = __float_as_int(w[e]);
            sedge1[pos] = pk;
        }
    }
}

// fine pass: bucket -> per-node CSR; also weighted degree -> dinv.
__global__ __launch_bounds__(256) void fine_kernel(
    const int2* __restrict__ sedge1, const int* __restrict__ bktStart,
    int2* __restrict__ sedge2, int* __restrict__ nodeStart,
    int* __restrict__ nodeCnt, float* __restrict__ dinv, int n)
{
    __shared__ int cnt[BNODES];
    __shared__ float wsum[BNODES];
    __shared__ int off[BNODES];
    __shared__ int cur[BNODES];
    __shared__ int wt[4];
    int b = blockIdx.x, t = threadIdx.x;
    if (t < BNODES) { cnt[t] = 0; wsum[t] = 1.0f; }   // 1 = self-loop weight
    __syncthreads();
    int s = bktStart[b], e = bktStart[b + 1];
    for (int j = s + t; j < e; j += 256) {
        int2 pk = sedge1[j];
        int ld = pk.x >> 20;
        atomicAdd(&cnt[ld], 1);
        atomicAdd(&wsum[ld], __int_as_float(pk.y));
    }
    __syncthreads();
    int v = (t < BNODES) ? cnt[t] : 0;
    int incl = blockIncScan(v, t, wt);                 // has __syncthreads
    if (t < BNODES) { off[t] = s + incl - v; cur[t] = s + incl - v; }
    __syncthreads();
    int node = b * BNODES + t;
    if (t < BNODES && node < n) {
        nodeStart[node] = off[t];
        nodeCnt[node] = cnt[t];
        dinv[node] = rsqrtf(wsum[t]);
    }
    for (int j = s + t; j < e; j += 256) {
        int2 pk = sedge1[j];
        int ld = pk.x >> 20;
        int pos = atomicAdd(&cur[ld], 1);              // LDS atomic
        sedge2[pos] = make_int2(pk.x & 0xFFFFF, pk.y);
    }
}

// ---- per-layer kernels ---------------------------------------------------

// G[node,:] = bf16( (X[node,:] @ W) * dinv[node] )   (64x64 tile per block)
template<int K>
__global__ __launch_bounds__(256) void gemm_scale_kernel(
    const float* __restrict__ X, const float* __restrict__ W,
    const float* __restrict__ dinv, unsigned short* __restrict__ G, int n)
{
    __shared__ float xs[64][K + 1];
    __shared__ float ws[K][64];
    const int tid = threadIdx.x;
    const int nodeBase = blockIdx.x * 64;

    for (int idx = tid; idx < K * 16; idx += 256) {
        int flat = idx * 4;
        int k = flat >> 6, c = flat & 63;
        *(float4*)&ws[k][c] = *(const float4*)&W[flat];
    }
    for (int idx = tid; idx < 16 * K; idx += 256) {
        int flat = idx * 4;
        int r = flat / K, c = flat % K;
        int node = nodeBase + r;
        float4 v = make_float4(0.f, 0.f, 0.f, 0.f);
        if (node < n) v = *(const float4*)&X[(size_t)node * K + c];
        *(float4*)&xs[r][c] = v;
    }
    __syncthreads();

    const int nr = tid >> 4;
    const int fc = tid & 15;
    float acc[4][4];
    #pragma unroll
    for (int m = 0; m < 4; ++m)
        #pragma unroll
        for (int j = 0; j < 4; ++j) acc[m][j] = 0.f;

    #pragma unroll 4
    for (int k = 0; k < K; ++k) {
        float4 b = *(const float4*)&ws[k][fc * 4];
        #pragma unroll
        for (int m = 0; m < 4; ++m) {
            float a = xs[nr * 4 + m][k];
            acc[m][0] = fmaf(a, b.x, acc[m][0]);
            acc[m][1] = fmaf(a, b.y, acc[m][1]);
            acc[m][2] = fmaf(a, b.z, acc[m][2]);
            acc[m][3] = fmaf(a, b.w, acc[m][3]);
        }
    }

    #pragma unroll
    for (int m = 0; m < 4; ++m) {
        int node = nodeBase + nr * 4 + m;
        if (node >= n) continue;
        float s = dinv[node];
        ushort4 v;
        v.x = f2bf(acc[m][0] * s);
        v.y = f2bf(acc[m][1] * s);
        v.z = f2bf(acc[m][2] * s);
        v.w = f2bf(acc[m][3] * s);
        *(ushort4*)&G[(size_t)node * 64 + fc * 4] = v;
    }
}

// out[node,:] = relu(dinv*(g[node,:] + sum_e w_e*g[row_e,:]) + bias)
// 16 lanes/node over CSR lists; register accumulate; zero atomics.
__global__ __launch_bounds__(256) void agg_kernel(
    const unsigned short* __restrict__ G, const int2* __restrict__ sedge2,
    const int* __restrict__ nodeStart, const int* __restrict__ nodeCnt,
    const float* __restrict__ dinv, const float* __restrict__ bias,
    float* __restrict__ OUT, int n)
{
    int t = blockIdx.x * blockDim.x + threadIdx.x;
    if (t >= n * 16) return;
    int node = t >> 4, p = t & 15;

    ushort4 sv = *(const ushort4*)&G[(size_t)node * 64 + p * 4];
    float4 a0 = make_float4(bf2f(sv.x), bf2f(sv.y), bf2f(sv.z), bf2f(sv.w));
    float4 a1 = make_float4(0.f, 0.f, 0.f, 0.f);

    int s = nodeStart[node];
    int e_end = s + nodeCnt[node];
    int j = s;
    for (; j + 1 < e_end; j += 2) {
        int2 pk0 = sedge2[j];
        int2 pk1 = sedge2[j + 1];
        float w0 = __int_as_float(pk0.y);
        float w1 = __int_as_float(pk1.y);
        ushort4 g0 = *(const ushort4*)&G[(size_t)pk0.x * 64 + p * 4];
        ushort4 g1 = *(const ushort4*)&G[(size_t)pk1.x * 64 + p * 4];
        a0.x = fmaf(w0, bf2f(g0.x), a0.x); a0.y = fmaf(w0, bf2f(g0.y), a0.y);
        a0.z = fmaf(w0, bf2f(g0.z), a0.z); a0.w = fmaf(w0, bf2f(g0.w), a0.w);
        a1.x = fmaf(w1, bf2f(g1.x), a1.x); a1.y = fmaf(w1, bf2f(g1.y), a1.y);
        a1.z = fmaf(w1, bf2f(g1.z), a1.z); a1.w = fmaf(w1, bf2f(g1.w), a1.w);
    }
    if (j < e_end) {
        int2 pk = sedge2[j];
        float w = __int_as_float(pk.y);
        ushort4 g = *(const ushort4*)&G[(size_t)pk.x * 64 + p * 4];
        a0.x = fmaf(w, bf2f(g.x), a0.x); a0.y = fmaf(w, bf2f(g.y), a0.y);
        a0.z = fmaf(w, bf2f(g.z), a0.z); a0.w = fmaf(w, bf2f(g.w), a0.w);
    }

    float di = dinv[node];
    float4 bb = *(const float4*)&bias[p * 4];
    float4 o;
    o.x = fmaxf(fmaf(di, a0.x + a1.x, bb.x), 0.f);
    o.y = fmaxf(fmaf(di, a0.y + a1.y, bb.y), 0.f);
    o.z = fmaxf(fmaf(di, a0.z + a1.z, bb.z), 0.f);
    o.w = fmaxf(fmaf(di, a0.w + a1.w, bb.w), 0.f);
    *(float4*)&OUT[(size_t)node * 64 + p * 4] = o;
}

extern "C" void kernel_launch(void* const* d_in, const int* in_sizes, int n_in,
                              void* d_out, int out_size, void* d_ws, size_t ws_size,
                              hipStream_t stream) {
    const float* x     = (const float*)d_in[0];
    const int*   eidx  = (const int*)d_in[1];
    const float* eattr = (const float*)d_in[2];
    const float* W1    = (const float*)d_in[3];
    const float* b1    = (const float*)d_in[4];
    const float* W2    = (const float*)d_in[5];
    const float* b2    = (const float*)d_in[6];
    float* out = (float*)d_out;

    const int n = in_sizes[0] / 128;
    const int E = in_sizes[2];
    const int* row = eidx;
    const int* col = eidx + E;

    const int NBKT = (n + BNODES - 1) / BNODES;    // 782
    const int NEB  = (E + EPB - 1) / EPB;          // 245 (<=256 required)

    // ws (~31 MB): sedge1[E] | sedge2[E] | gbuf[n*64] bf16 | dinv[n] |
    //              nodeStart[n] | nodeCnt[n] | H[NEB*NBKT] | rowSum | bktStart
    int2*  sedge1 = (int2*)d_ws;
    int2*  sedge2 = sedge1 + (size_t)E;
    unsigned short* gbuf = (unsigned short*)(sedge2 + (size_t)E);
    float* dinv   = (float*)(gbuf + (size_t)n * 64);
    int*   nodeStart = (int*)(dinv + n);
    int*   nodeCnt   = nodeStart + n;
    int*   H         = nodeCnt + n;
    int*   rowSum    = H + (size_t)NEB * NBKT;
    int*   bktStart  = rowSum + NBKT;

    const int nbG = (n + 63) / 64;
    const int nbA = (int)(((size_t)n * 16 + 255) / 256);

    // ---- build CSR (once; shared by both layers)
    hist_kernel<<<NEB, 256, 0, stream>>>(col, H, E, NBKT);
    rowscan_kernel<<<NBKT, 256, 0, stream>>>(H, rowSum, NEB, NBKT);
    bktscan_kernel<<<1, 256, 0, stream>>>(rowSum, bktStart, NBKT);
    scatter_kernel<<<NEB, 256, 0, stream>>>(row, col, eattr, H, bktStart, sedge1, E, NBKT);
    fine_kernel<<<NBKT, 256, 0, stream>>>(sedge1, bktStart, sedge2, nodeStart, nodeCnt, dinv, n);

    // ---- layer 1: g1 -> gbuf, out1 -> d_out (activation buffer)
    gemm_scale_kernel<128><<<nbG, 256, 0, stream>>>(x, W1, dinv, gbuf, n);
    agg_kernel<<<nbA, 256, 0, stream>>>(gbuf, sedge2, nodeStart, nodeCnt, dinv, b1, out, n);

    // ---- layer 2: g2 -> gbuf, final -> d_out
    gemm_scale_kernel<64><<<nbG, 256, 0, stream>>>(out, W2, dinv, gbuf, n);
    agg_kernel<<<nbA, 256, 0, stream>>>(gbuf, sedge2, nodeStart, nodeCnt, dinv, b2, out, n);
}

// Round 7
// 143.110 us; speedup vs baseline: 6.8810x; 1.1797x over previous
//
#include <hip/hip_runtime.h>

// GCN restructure:  deg[c] = 1 + sum_{col=c} w;  dinv = rsqrt(deg)
//   g = (X@W) * dinv[node]        (MFMA bf16 GEMM, epilogue scale, stored bf16)
//   out[c] = relu( dinv[c] * ( g[c] + sum_{e: col=c} w_e * g[row_e] ) + b )
//
// R7: GEMMs moved to the matrix pipe (mfma_f32_16x16x32_bf16), 64x64 tile,
// 4 waves/block, XOR-swizzled LDS (2-way = free).  Layer-1 activation stored
// bf16 (it gets converted for MFMA anyway).  Build pipeline (counting-sort ->
// CSR, zero global atomics) and register-accumulate agg unchanged from R6.
// Measured session facts: global atomic ~62B memory-side traffic; 64M LDS
// atomics = 445us; f32-VALU GEMM was latency-bound at 26% VALUBusy.

#define BNODES 128
#define LB 7
#define MAXBKT 1024
#define EPT 16
#define EPB (256 * EPT)

typedef __attribute__((ext_vector_type(8))) short bf16x8;
typedef __attribute__((ext_vector_type(4))) float f32x4;

__device__ __forceinline__ unsigned short f2bf(float f) {
    unsigned u = __float_as_uint(f);
    u = (u + 0x7FFF + ((u >> 16) & 1)) >> 16;   // rtne
    return (unsigned short)u;
}
__device__ __forceinline__ float bf2f(unsigned short h) {
    return __uint_as_float(((unsigned)h) << 16);
}

__device__ __forceinline__ int waveIncScan(int v, int lane) {
    #pragma unroll
    for (int d = 1; d < 64; d <<= 1) {
        int u = __shfl_up(v, d, 64);
        if (lane >= d) v += u;
    }
    return v;
}

__device__ __forceinline__ int blockIncScan(int v, int t, int* wt) {
    int lane = t & 63, w = t >> 6;
    int s = waveIncScan(v, lane);
    if (lane == 63) wt[w] = s;
    __syncthreads();
    int add = 0;
    #pragma unroll
    for (int i = 0; i < 3; ++i) if (i < w) add += wt[i];
    return s + add;
}

// ---- weight transpose + bf16 convert (once) ------------------------------

__global__ void wtconv_kernel(const float* __restrict__ W1, const float* __restrict__ W2,
                              unsigned short* __restrict__ WT1,
                              unsigned short* __restrict__ WT2) {
    int t = blockIdx.x * blockDim.x + threadIdx.x;
    if (t < 64 * 128) {
        int c = t >> 7, k = t & 127;            // WT1[c][k] = W1[k][c]
        WT1[t] = f2bf(W1[k * 64 + c]);
    } else if (t < 64 * 128 + 64 * 64) {
        int i = t - 64 * 128;
        int c = i >> 6, k = i & 63;             // WT2[c][k] = W2[k][c]
        WT2[i] = f2bf(W2[k * 64 + c]);
    }
}

// ---- sort pipeline (zero global atomics), unchanged from R6 --------------

__global__ __launch_bounds__(256) void hist_kernel(
    const int* __restrict__ col, int* __restrict__ H, int E, int NBKT)
{
    __shared__ int h[MAXBKT];
    int t = threadIdx.x, blk = blockIdx.x;
    for (int b = t; b < NBKT; b += 256) h[b] = 0;
    __syncthreads();
    int base = blk * EPB;
    #pragma unroll
    for (int i = 0; i < EPT; ++i) {
        int e = base + i * 256 + t;
        if (e < E) atomicAdd(&h[col[e] >> LB], 1);
    }
    __syncthreads();
    for (int b = t; b < NBKT; b += 256) H[blk * NBKT + b] = h[b];
}

__global__ __launch_bounds__(256) void rowscan_kernel(
    int* __restrict__ H, int* __restrict__ rowSum, int NEB, int NBKT)
{
    __shared__ int wt[4];
    int b = blockIdx.x, t = threadIdx.x;
    int v = (t < NEB) ? H[t * NBKT + b] : 0;
    int incl = blockIncScan(v, t, wt);
    if (t < NEB) H[t * NBKT + b] = incl - v;
    if (t == 255) rowSum[b] = incl;
}

__global__ __launch_bounds__(256) void bktscan_kernel(
    const int* __restrict__ rowSum, int* __restrict__ bktStart, int NBKT)
{
    __shared__ int wt[4];
    int t = threadIdx.x;
    int v[4]; int sum = 0;
    #pragma unroll
    for (int k = 0; k < 4; ++k) {
        int i = t * 4 + k;
        v[k] = (i < NBKT) ? rowSum[i] : 0;
        sum += v[k];
    }
    int incl = blockIncScan(sum, t, wt);
    int excl = incl - sum;
    #pragma unroll
    for (int k = 0; k < 4; ++k) {
        int i = t * 4 + k;
        if (i < NBKT) bktStart[i] = excl;
        excl += v[k];
    }
    if (t == 255) bktStart[NBKT] = incl;
}

__global__ __launch_bounds__(256) void scatter_kernel(
    const int* __restrict__ row, const int* __restrict__ col,
    const float* __restrict__ w, const int* __restrict__ H,
    const int* __restrict__ bktStart, int2* __restrict__ sedge1, int E, int NBKT)
{
    __shared__ int cur[MAXBKT];
    int t = threadIdx.x, blk = blockIdx.x;
    for (int b = t; b < NBKT; b += 256) cur[b] = bktStart[b] + H[blk * NBKT + b];
    __syncthreads();
    int base = blk * EPB;
    #pragma unroll
    for (int i = 0; i < EPT; ++i) {
        int e = base + i * 256 + t;
        if (e < E) {
            int c = col[e];
            int b = c >> LB;
            int pos = atomicAdd(&cur[b], 1);      // LDS atomic
            int2 pk;
            pk.x = row[e] | ((c & (BNODES - 1)) << 20);
            pk.y = __float_as_int(w[e]);
            sedge1[pos] = pk;
        }
    }
}

__global__ __launch_bounds__(256) void fine_kernel(
    const int2* __restrict__ sedge1, const int* __restrict__ bktStart,
    int2* __restrict__ sedge2, int* __restrict__ nodeStart,
    int* __restrict__ nodeCnt, float* __restrict__ dinv, int n)
{
    __shared__ int cnt[BNODES];
    __shared__ float wsum[BNODES];
    __shared__ int off[BNODES];
    __shared__ int cur[BNODES];
    __shared__ int wt[4];
    int b = blockIdx.x, t = threadIdx.x;
    if (t < BNODES) { cnt[t] = 0; wsum[t] = 1.0f; }
    __syncthreads();
    int s = bktStart[b], e = bktStart[b + 1];
    for (int j = s + t; j < e; j += 256) {
        int2 pk = sedge1[j];
        int ld = pk.x >> 20;
        atomicAdd(&cnt[ld], 1);
        atomicAdd(&wsum[ld], __int_as_float(pk.y));
    }
    __syncthreads();
    int v = (t < BNODES) ? cnt[t] : 0;
    int incl = blockIncScan(v, t, wt);
    if (t < BNODES) { off[t] = s + incl - v; cur[t] = s + incl - v; }
    __syncthreads();
    int node = b * BNODES + t;
    if (t < BNODES && node < n) {
        nodeStart[node] = off[t];
        nodeCnt[node] = cnt[t];
        dinv[node] = rsqrtf(wsum[t]);
    }
    for (int j = s + t; j < e; j += 256) {
        int2 pk = sedge1[j];
        int ld = pk.x >> 20;
        int pos = atomicAdd(&cur[ld], 1);
        sedge2[pos] = make_int2(pk.x & 0xFFFFF, pk.y);
    }
}

// ---- MFMA GEMM: G[node,:] = bf16( (X[node,:] @ W) * dinv[node] ) ---------
// 64x64 tile, 4 waves; A/B staged bf16 in LDS with XOR slot-swizzle so both
// fragment reads are conflict-free ds_read_b128.  WT is pre-transposed bf16.
// mfma_f32_16x16x32_bf16 layouts (m89-verified): A: lane l -> A[l&15][(l>>4)*8+j]
// B: lane l -> B[(l>>4)*8+j][l&15];  D: lane l,reg j -> D[(l>>4)*4+j][l&15].
template<int K, bool IN_BF16>
__global__ __launch_bounds__(256) void gemm_mfma_kernel(
    const void* __restrict__ Xv, const unsigned short* __restrict__ WT,
    const float* __restrict__ dinv, unsigned short* __restrict__ G, int n)
{
    constexpr int ROWB = 2 * K;          // LDS bytes per row
    constexpr int SLOTS = K / 8;         // 16B slots per row
    __shared__ char smem[64 * ROWB * 2];
    char* xs = smem;
    char* ws = smem + 64 * ROWB;
    const int tid = threadIdx.x;
    const int nodeBase = blockIdx.x * 64;

    // stage W^T (straight bf16 copy, swizzled dest)
    for (int q = tid; q < 64 * SLOTS; q += 256) {
        int r = q / SLOTS, s = q % SLOTS;
        uint4 v = *(const uint4*)(WT + r * K + s * 8);
        *(uint4*)(ws + r * ROWB + ((s ^ (r & 7)) * 16)) = v;
    }
    // stage X tile in 8B chunks (convert f32->bf16 if needed), swizzled dest
    constexpr int CPR = K / 4;           // 8B chunks per row
    if constexpr (IN_BF16) {
        const unsigned short* X = (const unsigned short*)Xv;
        for (int q = tid; q < 64 * CPR; q += 256) {
            int r = q / CPR, c = q % CPR;
            int node = nodeBase + r;
            uint2 v = make_uint2(0u, 0u);
            if (node < n) v = *(const uint2*)(X + (size_t)node * K + c * 4);
            *(uint2*)(xs + r * ROWB + (((c >> 1) ^ (r & 7)) * 16) + (c & 1) * 8) = v;
        }
    } else {
        const float* X = (const float*)Xv;
        for (int q = tid; q < 64 * CPR; q += 256) {
            int r = q / CPR, c = q % CPR;
            int node = nodeBase + r;
            float4 v = make_float4(0.f, 0.f, 0.f, 0.f);
            if (node < n) v = *(const float4*)(X + (size_t)node * K + c * 4);
            ushort4 h;
            h.x = f2bf(v.x); h.y = f2bf(v.y); h.z = f2bf(v.z); h.w = f2bf(v.w);
            *(ushort4*)(xs + r * ROWB + (((c >> 1) ^ (r & 7)) * 16) + (c & 1) * 8) = h;
        }
    }
    __syncthreads();

    const int lane = tid & 63;
    const int w = tid >> 6;
    const int lr = lane & 15;            // A-row / B-col within 16
    const int lk = lane >> 4;            // k-group 0..3
    const int arow = (w << 4) + lr;

    f32x4 acc[4] = {};
    #pragma unroll
    for (int kb = 0; kb < K / 32; ++kb) {
        int s = kb * 4 + lk;
        bf16x8 a = *(bf16x8*)(xs + arow * ROWB + ((s ^ (arow & 7)) * 16));
        #pragma unroll
        for (int cb = 0; cb < 4; ++cb) {
            int c = cb * 16 + lr;
            bf16x8 b = *(bf16x8*)(ws + c * ROWB + ((s ^ (c & 7)) * 16));
            acc[cb] = __builtin_amdgcn_mfma_f32_16x16x32_bf16(a, b, acc[cb], 0, 0, 0);
        }
    }

    int rowbase = nodeBase + (w << 4) + (lk << 2);
    #pragma unroll
    for (int j = 0; j < 4; ++j) {
        int node = rowbase + j;
        if (node >= n) continue;
        float dv = dinv[node];
        #pragma unroll
        for (int cb = 0; cb < 4; ++cb)
            G[(size_t)node * 64 + cb * 16 + lr] = f2bf(acc[cb][j] * dv);
    }
}

// ---- aggregation: out = relu(dinv*(g_self + sum w*g_nb) + bias) ----------
// 16 lanes/node over CSR; register accumulate; zero atomics.  OUT bf16 for
// layer 1 (feeds the next MFMA), f32 for the final output.
template<bool OUT_BF16>
__global__ __launch_bounds__(256) void agg_kernel(
    const unsigned short* __restrict__ G, const int2* __restrict__ sedge2,
    const int* __restrict__ nodeStart, const int* __restrict__ nodeCnt,
    const float* __restrict__ dinv, const float* __restrict__ bias,
    void* __restrict__ OUTv, int n)
{
    int t = blockIdx.x * blockDim.x + threadIdx.x;
    if (t >= n * 16) return;
    int node = t >> 4, p = t & 15;

    ushort4 sv = *(const ushort4*)&G[(size_t)node * 64 + p * 4];
    float4 a0 = make_float4(bf2f(sv.x), bf2f(sv.y), bf2f(sv.z), bf2f(sv.w));
    float4 a1 = make_float4(0.f, 0.f, 0.f, 0.f);

    int s = nodeStart[node];
    int e_end = s + nodeCnt[node];
    int j = s;
    for (; j + 1 < e_end; j += 2) {
        int2 pk0 = sedge2[j];
        int2 pk1 = sedge2[j + 1];
        float w0 = __int_as_float(pk0.y);
        float w1 = __int_as_float(pk1.y);
        ushort4 g0 = *(const ushort4*)&G[(size_t)pk0.x * 64 + p * 4];
        ushort4 g1 = *(const ushort4*)&G[(size_t)pk1.x * 64 + p * 4];
        a0.x = fmaf(w0, bf2f(g0.x), a0.x); a0.y = fmaf(w0, bf2f(g0.y), a0.y);
        a0.z = fmaf(w0, bf2f(g0.z), a0.z); a0.w = fmaf(w0, bf2f(g0.w), a0.w);
        a1.x = fmaf(w1, bf2f(g1.x), a1.x); a1.y = fmaf(w1, bf2f(g1.y), a1.y);
        a1.z = fmaf(w1, bf2f(g1.z), a1.z); a1.w = fmaf(w1, bf2f(g1.w), a1.w);
    }
    if (j < e_end) {
        int2 pk = sedge2[j];
        float w = __int_as_float(pk.y);
        ushort4 g = *(const ushort4*)&G[(size_t)pk.x * 64 + p * 4];
        a0.x = fmaf(w, bf2f(g.x), a0.x); a0.y = fmaf(w, bf2f(g.y), a0.y);
        a0.z = fmaf(w, bf2f(g.z), a0.z); a0.w = fmaf(w, bf2f(g.w), a0.w);
    }

    float di = dinv[node];
    float4 bb = *(const float4*)&bias[p * 4];
    float4 o;
    o.x = fmaxf(fmaf(di, a0.x + a1.x, bb.x), 0.f);
    o.y = fmaxf(fmaf(di, a0.y + a1.y, bb.y), 0.f);
    o.z = fmaxf(fmaf(di, a0.z + a1.z, bb.z), 0.f);
    o.w = fmaxf(fmaf(di, a0.w + a1.w, bb.w), 0.f);
    if constexpr (OUT_BF16) {
        ushort4 ov;
        ov.x = f2bf(o.x); ov.y = f2bf(o.y); ov.z = f2bf(o.z); ov.w = f2bf(o.w);
        *(ushort4*)((unsigned short*)OUTv + (size_t)node * 64 + p * 4) = ov;
    } else {
        *(float4*)((float*)OUTv + (size_t)node * 64 + p * 4) = o;
    }
}

extern "C" void kernel_launch(void* const* d_in, const int* in_sizes, int n_in,
                              void* d_out, int out_size, void* d_ws, size_t ws_size,
                              hipStream_t stream) {
    const float* x     = (const float*)d_in[0];
    const int*   eidx  = (const int*)d_in[1];
    const float* eattr = (const float*)d_in[2];
    const float* W1    = (const float*)d_in[3];
    const float* b1    = (const float*)d_in[4];
    const float* W2    = (const float*)d_in[5];
    const float* b2    = (const float*)d_in[6];
    float* out = (float*)d_out;

    const int n = in_sizes[0] / 128;
    const int E = in_sizes[2];
    const int* row = eidx;
    const int* col = eidx + E;

    const int NBKT = (n + BNODES - 1) / BNODES;    // 782
    const int NEB  = (E + EPB - 1) / EPB;          // 245 (<=256 required)

    // ws (~45 MB): sedge1[E] | sedge2[E] | gbuf[n*64]u16 | act[n*64]u16 |
    //   WT1[64*128]u16 | WT2[64*64]u16 | dinv[n] | nodeStart[n] | nodeCnt[n] |
    //   H[NEB*NBKT] | rowSum[NBKT] | bktStart[NBKT+1]
    int2*  sedge1 = (int2*)d_ws;
    int2*  sedge2 = sedge1 + (size_t)E;
    unsigned short* gbuf = (unsigned short*)(sedge2 + (size_t)E);
    unsigned short* act  = gbuf + (size_t)n * 64;
    unsigned short* WT1  = act + (size_t)n * 64;
    unsigned short* WT2  = WT1 + 64 * 128;
    float* dinv      = (float*)(WT2 + 64 * 64);
    int*   nodeStart = (int*)(dinv + n);
    int*   nodeCnt   = nodeStart + n;
    int*   H         = nodeCnt + n;
    int*   rowSum    = H + (size_t)NEB * NBKT;
    int*   bktStart  = rowSum + NBKT;

    const int nbG = (n + 63) / 64;
    const int nbA = (int)(((size_t)n * 16 + 255) / 256);

    // ---- build (once; shared by both layers)
    wtconv_kernel<<<48, 256, 0, stream>>>(W1, W2, WT1, WT2);
    hist_kernel<<<NEB, 256, 0, stream>>>(col, H, E, NBKT);
    rowscan_kernel<<<NBKT, 256, 0, stream>>>(H, rowSum, NEB, NBKT);
    bktscan_kernel<<<1, 256, 0, stream>>>(rowSum, bktStart, NBKT);
    scatter_kernel<<<NEB, 256, 0, stream>>>(row, col, eattr, H, bktStart, sedge1, E, NBKT);
    fine_kernel<<<NBKT, 256, 0, stream>>>(sedge1, bktStart, sedge2, nodeStart, nodeCnt, dinv, n);

    // ---- layer 1: g1 -> gbuf (bf16), out1 -> act (bf16)
    gemm_mfma_kernel<128, false><<<nbG, 256, 0, stream>>>(x, WT1, dinv, gbuf, n);
    agg_kernel<true><<<nbA, 256, 0, stream>>>(gbuf, sedge2, nodeStart, nodeCnt, dinv, b1, act, n);

    // ---- layer 2: g2 -> gbuf (bf16), final -> d_out (f32)
    gemm_mfma_kernel<64, true><<<nbG, 256, 0, stream>>>(act, WT2, dinv, gbuf, n);
    agg_kernel<false><<<nbA, 256, 0, stream>>>(gbuf, sedge2, nodeStart, nodeCnt, dinv, b2, out, n);
}

// Round 8
// 129.073 us; speedup vs baseline: 7.6294x; 1.1088x over previous
//
#include <hip/hip_runtime.h>

// GCN restructure:  deg[c] = 1 + sum_{col=c} w;  dinv = rsqrt(deg)
//   g = (X@W) * dinv[node]        (MFMA bf16 GEMM, epilogue scale, stored bf16)
//   out[c] = relu( dinv[c] * ( g[c] + sum_{e: col=c} w_e * g[row_e] ) + b )
//
// R8: agg1+gemm2 FUSED (activation lives only in LDS: saves 25.6 MB HBM
// round-trip + a launch); wtconv folded into hist's launch.  Build
// (counting-sort -> CSR, zero global atomics), gemm1 MFMA, agg2 unchanged.
// Session facts: global atomic ~62B memory-side; 64M LDS atomics = 445us;
// f32-VALU GEMM latency-bound at 26% VALUBusy -> MFMA.

#define BNODES 128
#define LB 7
#define MAXBKT 1024
#define EPT 16
#define EPB (256 * EPT)

typedef __attribute__((ext_vector_type(8))) short bf16x8;
typedef __attribute__((ext_vector_type(4))) float f32x4;

__device__ __forceinline__ unsigned short f2bf(float f) {
    unsigned u = __float_as_uint(f);
    u = (u + 0x7FFF + ((u >> 16) & 1)) >> 16;   // rtne
    return (unsigned short)u;
}
__device__ __forceinline__ float bf2f(unsigned short h) {
    return __uint_as_float(((unsigned)h) << 16);
}

__device__ __forceinline__ int waveIncScan(int v, int lane) {
    #pragma unroll
    for (int d = 1; d < 64; d <<= 1) {
        int u = __shfl_up(v, d, 64);
        if (lane >= d) v += u;
    }
    return v;
}

__device__ __forceinline__ int blockIncScan(int v, int t, int* wt) {
    int lane = t & 63, w = t >> 6;
    int s = waveIncScan(v, lane);
    if (lane == 63) wt[w] = s;
    __syncthreads();
    int add = 0;
    #pragma unroll
    for (int i = 0; i < 3; ++i) if (i < w) add += wt[i];
    return s + add;
}

// ---- hist (+ weight transpose in tail blocks) ----------------------------

__global__ __launch_bounds__(256) void hist_kernel(
    const int* __restrict__ col, int* __restrict__ H, int E, int NBKT,
    const float* __restrict__ W1, const float* __restrict__ W2,
    unsigned short* __restrict__ WT1, unsigned short* __restrict__ WT2, int NEB)
{
    int t = threadIdx.x, blk = blockIdx.x;
    if (blk >= NEB) {                       // wtconv tail blocks
        int i = (blk - NEB) * 256 + t;
        if (i < 64 * 128) {
            int c = i >> 7, k = i & 127;    // WT1[c][k] = W1[k][c]
            WT1[i] = f2bf(W1[k * 64 + c]);
        } else if (i < 64 * 128 + 64 * 64) {
            int j = i - 64 * 128;
            int c = j >> 6, k = j & 63;     // WT2[c][k] = W2[k][c]
            WT2[j] = f2bf(W2[k * 64 + c]);
        }
        return;
    }
    __shared__ int h[MAXBKT];
    for (int b = t; b < NBKT; b += 256) h[b] = 0;
    __syncthreads();
    int base = blk * EPB;
    #pragma unroll
    for (int i = 0; i < EPT; ++i) {
        int e = base + i * 256 + t;
        if (e < E) atomicAdd(&h[col[e] >> LB], 1);
    }
    __syncthreads();
    for (int b = t; b < NBKT; b += 256) H[blk * NBKT + b] = h[b];
}

__global__ __launch_bounds__(256) void rowscan_kernel(
    int* __restrict__ H, int* __restrict__ rowSum, int NEB, int NBKT)
{
    __shared__ int wt[4];
    int b = blockIdx.x, t = threadIdx.x;
    int v = (t < NEB) ? H[t * NBKT + b] : 0;
    int incl = blockIncScan(v, t, wt);
    if (t < NEB) H[t * NBKT + b] = incl - v;
    if (t == 255) rowSum[b] = incl;
}

__global__ __launch_bounds__(256) void bktscan_kernel(
    const int* __restrict__ rowSum, int* __restrict__ bktStart, int NBKT)
{
    __shared__ int wt[4];
    int t = threadIdx.x;
    int v[4]; int sum = 0;
    #pragma unroll
    for (int k = 0; k < 4; ++k) {
        int i = t * 4 + k;
        v[k] = (i < NBKT) ? rowSum[i] : 0;
        sum += v[k];
    }
    int incl = blockIncScan(sum, t, wt);
    int excl = incl - sum;
    #pragma unroll
    for (int k = 0; k < 4; ++k) {
        int i = t * 4 + k;
        if (i < NBKT) bktStart[i] = excl;
        excl += v[k];
    }
    if (t == 255) bktStart[NBKT] = incl;
}

__global__ __launch_bounds__(256) void scatter_kernel(
    const int* __restrict__ row, const int* __restrict__ col,
    const float* __restrict__ w, const int* __restrict__ H,
    const int* __restrict__ bktStart, int2* __restrict__ sedge1, int E, int NBKT)
{
    __shared__ int cur[MAXBKT];
    int t = threadIdx.x, blk = blockIdx.x;
    for (int b = t; b < NBKT; b += 256) cur[b] = bktStart[b] + H[blk * NBKT + b];
    __syncthreads();
    int base = blk * EPB;
    #pragma unroll
    for (int i = 0; i < EPT; ++i) {
        int e = base + i * 256 + t;
        if (e < E) {
            int c = col[e];
            int b = c >> LB;
            int pos = atomicAdd(&cur[b], 1);      // LDS atomic
            int2 pk;
            pk.x = row[e] | ((c & (BNODES - 1)) << 20);
            pk.y = __float_as_int(w[e]);
            sedge1[pos] = pk;
        }
    }
}

__global__ __launch_bounds__(256) void fine_kernel(
    const int2* __restrict__ sedge1, const int* __restrict__ bktStart,
    int2* __restrict__ sedge2, int* __restrict__ nodeStart,
    int* __restrict__ nodeCnt, float* __restrict__ dinv, int n)
{
    __shared__ int cnt[BNODES];
    __shared__ float wsum[BNODES];
    __shared__ int off[BNODES];
    __shared__ int cur[BNODES];
    __shared__ int wt[4];
    int b = blockIdx.x, t = threadIdx.x;
    if (t < BNODES) { cnt[t] = 0; wsum[t] = 1.0f; }
    __syncthreads();
    int s = bktStart[b], e = bktStart[b + 1];
    for (int j = s + t; j < e; j += 256) {
        int2 pk = sedge1[j];
        int ld = pk.x >> 20;
        atomicAdd(&cnt[ld], 1);
        atomicAdd(&wsum[ld], __int_as_float(pk.y));
    }
    __syncthreads();
    int v = (t < BNODES) ? cnt[t] : 0;
    int incl = blockIncScan(v, t, wt);
    if (t < BNODES) { off[t] = s + incl - v; cur[t] = s + incl - v; }
    __syncthreads();
    int node = b * BNODES + t;
    if (t < BNODES && node < n) {
        nodeStart[node] = off[t];
        nodeCnt[node] = cnt[t];
        dinv[node] = rsqrtf(wsum[t]);
    }
    for (int j = s + t; j < e; j += 256) {
        int2 pk = sedge1[j];
        int ld = pk.x >> 20;
        int pos = atomicAdd(&cur[ld], 1);
        sedge2[pos] = make_int2(pk.x & 0xFFFFF, pk.y);
    }
}

// ---- MFMA GEMM (layer 1): G = bf16( (X@W1) * dinv ) ----------------------
template<int K, bool IN_BF16>
__global__ __launch_bounds__(256) void gemm_mfma_kernel(
    const void* __restrict__ Xv, const unsigned short* __restrict__ WT,
    const float* __restrict__ dinv, unsigned short* __restrict__ G, int n)
{
    constexpr int ROWB = 2 * K;
    constexpr int SLOTS = K / 8;
    __shared__ char smem[64 * ROWB * 2];
    char* xs = smem;
    char* ws = smem + 64 * ROWB;
    const int tid = threadIdx.x;
    const int nodeBase = blockIdx.x * 64;

    for (int q = tid; q < 64 * SLOTS; q += 256) {
        int r = q / SLOTS, s = q % SLOTS;
        uint4 v = *(const uint4*)(WT + r * K + s * 8);
        *(uint4*)(ws + r * ROWB + ((s ^ (r & 7)) * 16)) = v;
    }
    constexpr int CPR = K / 4;
    if constexpr (IN_BF16) {
        const unsigned short* X = (const unsigned short*)Xv;
        for (int q = tid; q < 64 * CPR; q += 256) {
            int r = q / CPR, c = q % CPR;
            int node = nodeBase + r;
            uint2 v = make_uint2(0u, 0u);
            if (node < n) v = *(const uint2*)(X + (size_t)node * K + c * 4);
            *(uint2*)(xs + r * ROWB + (((c >> 1) ^ (r & 7)) * 16) + (c & 1) * 8) = v;
        }
    } else {
        const float* X = (const float*)Xv;
        for (int q = tid; q < 64 * CPR; q += 256) {
            int r = q / CPR, c = q % CPR;
            int node = nodeBase + r;
            float4 v = make_float4(0.f, 0.f, 0.f, 0.f);
            if (node < n) v = *(const float4*)(X + (size_t)node * K + c * 4);
            ushort4 h;
            h.x = f2bf(v.x); h.y = f2bf(v.y); h.z = f2bf(v.z); h.w = f2bf(v.w);
            *(ushort4*)(xs + r * ROWB + (((c >> 1) ^ (r & 7)) * 16) + (c & 1) * 8) = h;
        }
    }
    __syncthreads();

    const int lane = tid & 63;
    const int w = tid >> 6;
    const int lr = lane & 15;
    const int lk = lane >> 4;
    const int arow = (w << 4) + lr;

    f32x4 acc[4] = {};
    #pragma unroll
    for (int kb = 0; kb < K / 32; ++kb) {
        int s = kb * 4 + lk;
        bf16x8 a = *(bf16x8*)(xs + arow * ROWB + ((s ^ (arow & 7)) * 16));
        #pragma unroll
        for (int cb = 0; cb < 4; ++cb) {
            int c = cb * 16 + lr;
            bf16x8 b = *(bf16x8*)(ws + c * ROWB + ((s ^ (c & 7)) * 16));
            acc[cb] = __builtin_amdgcn_mfma_f32_16x16x32_bf16(a, b, acc[cb], 0, 0, 0);
        }
    }

    int rowbase = nodeBase + (w << 4) + (lk << 2);
    #pragma unroll
    for (int j = 0; j < 4; ++j) {
        int node = rowbase + j;
        if (node >= n) continue;
        float dv = dinv[node];
        #pragma unroll
        for (int cb = 0; cb < 4; ++cb)
            G[(size_t)node * 64 + cb * 16 + lr] = f2bf(acc[cb][j] * dv);
    }
}

// ---- FUSED agg1 + gemm2: act lives only in LDS ---------------------------
// Phase 1: 4 passes x 16 nodes (16 lanes/node) aggregate layer-1 output,
//          relu, store bf16 to LDS act (swizzled: chunk c -> slot (c>>1)^(r&7)).
// Phase 2: MFMA 64x64x64 on act x W2; epilogue g2 = D*dinv -> G2 (bf16).
__global__ __launch_bounds__(256) void aggmm_kernel(
    const unsigned short* __restrict__ G1, const int2* __restrict__ sedge2,
    const int* __restrict__ nodeStart, const int* __restrict__ nodeCnt,
    const float* __restrict__ dinv, const float* __restrict__ bias,
    const unsigned short* __restrict__ WT2, unsigned short* __restrict__ G2, int n)
{
    constexpr int ROWB = 128;            // 64 bf16 per row
    __shared__ char smem[64 * ROWB * 2]; // act | ws  (16 KB)
    char* xs = smem;
    char* ws = smem + 64 * ROWB;
    const int tid = threadIdx.x;
    const int nodeBase = blockIdx.x * 64;

    // stage W2^T swizzled
    for (int q = tid; q < 64 * 8; q += 256) {
        int r = q >> 3, s = q & 7;
        uint4 v = *(const uint4*)(WT2 + r * 64 + s * 8);
        *(uint4*)(ws + r * ROWB + ((s ^ (r & 7)) * 16)) = v;
    }

    // ---- phase 1: aggregate 64 nodes into LDS act
    int p = tid & 15;
    float4 bb = *(const float4*)&bias[p * 4];
    #pragma unroll
    for (int pass = 0; pass < 4; ++pass) {
        int r = pass * 16 + (tid >> 4);
        int node = nodeBase + r;
        float4 o = make_float4(0.f, 0.f, 0.f, 0.f);
        if (node < n) {
            ushort4 sv = *(const ushort4*)&G1[(size_t)node * 64 + p * 4];
            float4 a0 = make_float4(bf2f(sv.x), bf2f(sv.y), bf2f(sv.z), bf2f(sv.w));
            float4 a1 = make_float4(0.f, 0.f, 0.f, 0.f);
            int s = nodeStart[node];
            int e_end = s + nodeCnt[node];
            int j = s;
            for (; j + 1 < e_end; j += 2) {
                int2 pk0 = sedge2[j];
                int2 pk1 = sedge2[j + 1];
                float w0 = __int_as_float(pk0.y);
                float w1 = __int_as_float(pk1.y);
                ushort4 g0 = *(const ushort4*)&G1[(size_t)pk0.x * 64 + p * 4];
                ushort4 g1 = *(const ushort4*)&G1[(size_t)pk1.x * 64 + p * 4];
                a0.x = fmaf(w0, bf2f(g0.x), a0.x); a0.y = fmaf(w0, bf2f(g0.y), a0.y);
                a0.z = fmaf(w0, bf2f(g0.z), a0.z); a0.w = fmaf(w0, bf2f(g0.w), a0.w);
                a1.x = fmaf(w1, bf2f(g1.x), a1.x); a1.y = fmaf(w1, bf2f(g1.y), a1.y);
                a1.z = fmaf(w1, bf2f(g1.z), a1.z); a1.w = fmaf(w1, bf2f(g1.w), a1.w);
            }
            if (j < e_end) {
                int2 pk = sedge2[j];
                float w = __int_as_float(pk.y);
                ushort4 g = *(const ushort4*)&G1[(size_t)pk.x * 64 + p * 4];
                a0.x = fmaf(w, bf2f(g.x), a0.x); a0.y = fmaf(w, bf2f(g.y), a0.y);
                a0.z = fmaf(w, bf2f(g.z), a0.z); a0.w = fmaf(w, bf2f(g.w), a0.w);
            }
            float di = dinv[node];
            o.x = fmaxf(fmaf(di, a0.x + a1.x, bb.x), 0.f);
            o.y = fmaxf(fmaf(di, a0.y + a1.y, bb.y), 0.f);
            o.z = fmaxf(fmaf(di, a0.z + a1.z, bb.z), 0.f);
            o.w = fmaxf(fmaf(di, a0.w + a1.w, bb.w), 0.f);
        }
        ushort4 h;
        h.x = f2bf(o.x); h.y = f2bf(o.y); h.z = f2bf(o.z); h.w = f2bf(o.w);
        *(ushort4*)(xs + r * ROWB + (((p >> 1) ^ (r & 7)) * 16) + (p & 1) * 8) = h;
    }
    __syncthreads();

    // ---- phase 2: MFMA on act (K=64)
    const int lane = tid & 63;
    const int w = tid >> 6;
    const int lr = lane & 15;
    const int lk = lane >> 4;
    const int arow = (w << 4) + lr;

    f32x4 acc[4] = {};
    #pragma unroll
    for (int kb = 0; kb < 2; ++kb) {
        int s = kb * 4 + lk;
        bf16x8 a = *(bf16x8*)(xs + arow * ROWB + ((s ^ (arow & 7)) * 16));
        #pragma unroll
        for (int cb = 0; cb < 4; ++cb) {
            int c = cb * 16 + lr;
            bf16x8 b = *(bf16x8*)(ws + c * ROWB + ((s ^ (c & 7)) * 16));
            acc[cb] = __builtin_amdgcn_mfma_f32_16x16x32_bf16(a, b, acc[cb], 0, 0, 0);
        }
    }

    int rowbase = nodeBase + (w << 4) + (lk << 2);
    #pragma unroll
    for (int j = 0; j < 4; ++j) {
        int node = rowbase + j;
        if (node >= n) continue;
        float dv = dinv[node];
        #pragma unroll
        for (int cb = 0; cb < 4; ++cb)
            G2[(size_t)node * 64 + cb * 16 + lr] = f2bf(acc[cb][j] * dv);
    }
}

// ---- final aggregation (f32 out) -----------------------------------------
__global__ __launch_bounds__(256) void agg_kernel(
    const unsigned short* __restrict__ G, const int2* __restrict__ sedge2,
    const int* __restrict__ nodeStart, const int* __restrict__ nodeCnt,
    const float* __restrict__ dinv, const float* __restrict__ bias,
    float* __restrict__ OUT, int n)
{
    int t = blockIdx.x * blockDim.x + threadIdx.x;
    if (t >= n * 16) return;
    int node = t >> 4, p = t & 15;

    ushort4 sv = *(const ushort4*)&G[(size_t)node * 64 + p * 4];
    float4 a0 = make_float4(bf2f(sv.x), bf2f(sv.y), bf2f(sv.z), bf2f(sv.w));
    float4 a1 = make_float4(0.f, 0.f, 0.f, 0.f);

    int s = nodeStart[node];
    int e_end = s + nodeCnt[node];
    int j = s;
    for (; j + 1 < e_end; j += 2) {
        int2 pk0 = sedge2[j];
        int2 pk1 = sedge2[j + 1];
        float w0 = __int_as_float(pk0.y);
        float w1 = __int_as_float(pk1.y);
        ushort4 g0 = *(const ushort4*)&G[(size_t)pk0.x * 64 + p * 4];
        ushort4 g1 = *(const ushort4*)&G[(size_t)pk1.x * 64 + p * 4];
        a0.x = fmaf(w0, bf2f(g0.x), a0.x); a0.y = fmaf(w0, bf2f(g0.y), a0.y);
        a0.z = fmaf(w0, bf2f(g0.z), a0.z); a0.w = fmaf(w0, bf2f(g0.w), a0.w);
        a1.x = fmaf(w1, bf2f(g1.x), a1.x); a1.y = fmaf(w1, bf2f(g1.y), a1.y);
        a1.z = fmaf(w1, bf2f(g1.z), a1.z); a1.w = fmaf(w1, bf2f(g1.w), a1.w);
    }
    if (j < e_end) {
        int2 pk = sedge2[j];
        float w = __int_as_float(pk.y);
        ushort4 g = *(const ushort4*)&G[(size_t)pk.x * 64 + p * 4];
        a0.x = fmaf(w, bf2f(g.x), a0.x); a0.y = fmaf(w, bf2f(g.y), a0.y);
        a0.z = fmaf(w, bf2f(g.z), a0.z); a0.w = fmaf(w, bf2f(g.w), a0.w);
    }

    float di = dinv[node];
    float4 bb = *(const float4*)&bias[p * 4];
    float4 o;
    o.x = fmaxf(fmaf(di, a0.x + a1.x, bb.x), 0.f);
    o.y = fmaxf(fmaf(di, a0.y + a1.y, bb.y), 0.f);
    o.z = fmaxf(fmaf(di, a0.z + a1.z, bb.z), 0.f);
    o.w = fmaxf(fmaf(di, a0.w + a1.w, bb.w), 0.f);
    *(float4*)&OUT[(size_t)node * 64 + p * 4] = o;
}

extern "C" void kernel_launch(void* const* d_in, const int* in_sizes, int n_in,
                              void* d_out, int out_size, void* d_ws, size_t ws_size,
                              hipStream_t stream) {
    const float* x     = (const float*)d_in[0];
    const int*   eidx  = (const int*)d_in[1];
    const float* eattr = (const float*)d_in[2];
    const float* W1    = (const float*)d_in[3];
    const float* b1    = (const float*)d_in[4];
    const float* W2    = (const float*)d_in[5];
    const float* b2    = (const float*)d_in[6];
    float* out = (float*)d_out;

    const int n = in_sizes[0] / 128;
    const int E = in_sizes[2];
    const int* row = eidx;
    const int* col = eidx + E;

    const int NBKT = (n + BNODES - 1) / BNODES;    // 782
    const int NEB  = (E + EPB - 1) / EPB;          // 245 (<=256 required)

    // ws (~45 MB): sedge1[E] | sedge2[E] | g1[n*64]u16 | g2[n*64]u16 |
    //   WT1 | WT2 | dinv[n] | nodeStart[n] | nodeCnt[n] | H | rowSum | bktStart
    int2*  sedge1 = (int2*)d_ws;
    int2*  sedge2 = sedge1 + (size_t)E;
    unsigned short* g1 = (unsigned short*)(sedge2 + (size_t)E);
    unsigned short* g2 = g1 + (size_t)n * 64;
    unsigned short* WT1 = g2 + (size_t)n * 64;
    unsigned short* WT2 = WT1 + 64 * 128;
    float* dinv      = (float*)(WT2 + 64 * 64);
    int*   nodeStart = (int*)(dinv + n);
    int*   nodeCnt   = nodeStart + n;
    int*   H         = nodeCnt + n;
    int*   rowSum    = H + (size_t)NEB * NBKT;
    int*   bktStart  = rowSum + NBKT;

    const int nbG = (n + 63) / 64;
    const int nbA = (int)(((size_t)n * 16 + 255) / 256);

    // ---- build (once; shared by both layers); wtconv rides on hist's launch
    hist_kernel<<<NEB + 48, 256, 0, stream>>>(col, H, E, NBKT, W1, W2, WT1, WT2, NEB);
    rowscan_kernel<<<NBKT, 256, 0, stream>>>(H, rowSum, NEB, NBKT);
    bktscan_kernel<<<1, 256, 0, stream>>>(rowSum, bktStart, NBKT);
    scatter_kernel<<<NEB, 256, 0, stream>>>(row, col, eattr, H, bktStart, sedge1, E, NBKT);
    fine_kernel<<<NBKT, 256, 0, stream>>>(sedge1, bktStart, sedge2, nodeStart, nodeCnt, dinv, n);

    // ---- layer 1 GEMM: g1 = (x@W1)*dinv  (bf16)
    gemm_mfma_kernel<128, false><<<nbG, 256, 0, stream>>>(x, WT1, dinv, g1, n);
    // ---- fused agg1 + gemm2: g2 = (relu(agg(g1))@W2)*dinv  (bf16)
    aggmm_kernel<<<nbG, 256, 0, stream>>>(g1, sedge2, nodeStart, nodeCnt, dinv, b1, WT2, g2, n);
    // ---- final aggregation -> d_out (f32)
    agg_kernel<<<nbA, 256, 0, stream>>>(g2, sedge2, nodeStart, nodeCnt, dinv, b2, out, n);
}